// Round 5
// baseline (16979.195 us; speedup 1.0000x reference)
//
#include <hip/hip_runtime.h>
#include <math.h>

#define BB 128
#define TT 1024
#define II 256
#define HH 512
#define KK 768

typedef __attribute__((ext_vector_type(8))) short short8v;
typedef __attribute__((ext_vector_type(4))) float float4v;

// ---- workspace layout ----
#define BARS_OFF   0
#define BARS_SZ    16384                         // 128 WGs x 128B flag lines
#define WFRAG_OFF  BARS_SZ
#define WFRAG_SZ   (96 * 24 * 64 * 16)           // 2,359,296 B bf16 B-fragments
#define GS_OFF     (WFRAG_OFF + WFRAG_SZ)
#define GS_STRIDE  131072                        // per-group state blob
#define GS_RHF     32768
#define GS_HFP     65536
#define GS_ZFP     98304
#define WS_NEED    ((size_t)GS_OFF + 8 * GS_STRIDE)

__device__ __forceinline__ unsigned short bf16_rne(float f) {
    unsigned u = __builtin_bit_cast(unsigned, f);
    unsigned r = u + 0x7FFFu + ((u >> 16) & 1u);
    return (unsigned short)(r >> 16);
}
__device__ __forceinline__ float bf16_tof(unsigned short h) {
    unsigned u = ((unsigned)h) << 16;
    return __builtin_bit_cast(float, u);
}
__device__ __forceinline__ void cp16(void* lds, const void* g) {
    __builtin_amdgcn_global_load_lds(
        (const __attribute__((address_space(1))) unsigned*)g,
        (__attribute__((address_space(3))) unsigned*)lds, 16, 0, 0);
}

#define MFMA __builtin_amdgcn_mfma_f32_16x16x32_bf16

// ---- one-time weight repack: fp32 [768][512] -> bf16 MFMA B-fragments ----
// frag(ntAll, kt): lane l, elem j -> W[kt*32 + (l>>4)*8 + j][n0 + (l&15)]
// ntAll 0..31: Wz, 32..63: Wr, 64..95: Wh
__global__ void repack_w(const float* __restrict__ Wz, const float* __restrict__ Wr,
                         const float* __restrict__ Wh, short8v* __restrict__ wB) {
    const int ntAll = blockIdx.x;
    const int w = threadIdx.x >> 6, l = threadIdx.x & 63;
    const float* W; int n0;
    if (ntAll < 32)      { W = Wz; n0 = ntAll * 16; }
    else if (ntAll < 64) { W = Wr; n0 = (ntAll - 32) * 16; }
    else                 { W = Wh; n0 = (ntAll - 64) * 16; }
    const int n = n0 + (l & 15);
    for (int kt = w; kt < 24; kt += 4) {
        const int k0 = kt * 32 + (l >> 4) * 8;
        short8v f;
        #pragma unroll
        for (int j = 0; j < 8; ++j)
            f[j] = (short)bf16_rne(W[(size_t)(k0 + j) * HH + n]);
        wB[((size_t)ntAll * 24 + kt) * 64 + l] = f;
    }
}

// ---- persistent MFMA GRU ----
// 128 WGs x 256 thr. group g = bid&7 (16 batch rows, XCD-local), slice s = bid>>3.
// Flag-array barrier: WG s release-stores its own 128B-strided flag; lanes 0..15
// poll the 16 flags in parallel (no RMW contention), acquire-fence, syncthreads.
__global__ __launch_bounds__(256, 1) void gru_mfma(
    const float* __restrict__ x,
    const float* __restrict__ bz, const float* __restrict__ br,
    const float* __restrict__ bh,
    float* __restrict__ out,
    const short8v* __restrict__ wB,
    char* __restrict__ gsBase,
    unsigned* __restrict__ bars)
{
    __shared__ short8v bP1[4][24][64];   // 96 KB: per-wave P1 B strips
    __shared__ short8v bP2[2][24][64];   // 48 KB: P2 B strips
    __shared__ short8v xF[8][64];        //  8 KB: x_t A-fragments (bf16)
    __shared__ float   shpad[1024];      //  4 KB: red / h-stage / rh-stage

    const int tid = threadIdx.x;
    const int w = tid >> 6, l = tid & 63;
    const int g = blockIdx.x & 7, s = blockIdx.x >> 3;
    const int m_ = l & 15, kg = l >> 4;

    char* gs = gsBase + (size_t)g * GS_STRIDE;
    short8v* hF  = (short8v*)gs;                 // h A-frags  [kt16][hl2][64]
    short8v* rhF = (short8v*)(gs + GS_RHF);      // r*h A-frags
    float*   hFP = (float*)(gs + GS_HFP);        // h fp32 [16][512]
    float*   zFP = (float*)(gs + GS_ZFP);        // z fp32 [16][512]
    unsigned* gf = bars + g * 512;               // 16 flags, 32-uint stride (128B)

    const int wi = s * 4 + w;
    const bool isZ = (wi < 32);
    const int colg1 = (isZ ? wi : wi - 32) * 16 + m_;
    const float bias1 = isZ ? bz[colg1] : br[colg1];
    const int ntP2 = w & 1, kh = w >> 1;
    const int colg2 = (s * 2 + ntP2) * 16 + m_;
    const float bias2 = bh[colg2];
    const bool isRWG = (s >= 8);

    const short8v* wP1 = wB + (size_t)wi * 24 * 64;
    const short8v* wP2 = wB + (size_t)(64 + s * 2 + ntP2) * 24 * 64;

#define STAGE_X(tt)                                                            \
    for (int slot = tid; slot < 512; slot += 256) {                            \
        const int kt = slot >> 6, ll = slot & 63;                              \
        const float* xp = x + (size_t)(g * 16 + (ll & 15)) * (TT * II)         \
                            + (size_t)(tt) * II + kt * 32 + (ll >> 4) * 8;     \
        const float4 v0 = *(const float4*)xp;                                  \
        const float4 v1 = *(const float4*)(xp + 4);                            \
        short8v f;                                                             \
        f[0] = (short)bf16_rne(v0.x); f[1] = (short)bf16_rne(v0.y);            \
        f[2] = (short)bf16_rne(v0.z); f[3] = (short)bf16_rne(v0.w);            \
        f[4] = (short)bf16_rne(v1.x); f[5] = (short)bf16_rne(v1.y);            \
        f[6] = (short)bf16_rne(v1.z); f[7] = (short)bf16_rne(v1.w);            \
        xF[kt][ll] = f;                                                        \
    }

#define GROUP_BARRIER()                                                        \
    do {                                                                       \
        if (tid == 0)                                                          \
            __hip_atomic_store(&gf[s * 32], tgt, __ATOMIC_RELEASE,             \
                               __HIP_MEMORY_SCOPE_AGENT);                      \
        if (tid < 16) {                                                        \
            const unsigned* fp = gf + tid * 32;                                \
            while (__hip_atomic_load(fp, __ATOMIC_RELAXED,                     \
                                     __HIP_MEMORY_SCOPE_AGENT) < tgt) {}       \
        }                                                                      \
        __builtin_amdgcn_fence(__ATOMIC_ACQUIRE, "agent");                     \
        __syncthreads();                                                       \
    } while (0)

    // one-time weight prefetch into LDS (stays resident for all 1024 steps)
    for (int kt = 0; kt < 24; ++kt)
        cp16(&bP1[w][kt][0], wP1 + kt * 64 + l);
    {
        const int k0 = kh * 12;
        for (int i = 0; i < 12; ++i)
            cp16(&bP2[ntP2][k0 + i][0], wP2 + (k0 + i) * 64 + l);
    }
    STAGE_X(0);
    __syncthreads();   // drains cp16 vmcnt + xF ds_writes

    unsigned tgt = 0;

    for (int t = 0; t < TT; ++t) {
        // ---- P1: [z|r] = sigmoid([x,h] @ [Wz|Wr] + b) ----
        float4v a0 = {0.f,0.f,0.f,0.f}, a1 = a0, a2 = a0, a3 = a0;
        #pragma unroll
        for (int kt = 0; kt < 8; ++kt) {
            const short8v av = xF[kt][l];
            const short8v bv = bP1[w][kt][l];
            switch (kt & 3) {
                case 0: a0 = MFMA(av, bv, a0, 0, 0, 0); break;
                case 1: a1 = MFMA(av, bv, a1, 0, 0, 0); break;
                case 2: a2 = MFMA(av, bv, a2, 0, 0, 0); break;
                default: a3 = MFMA(av, bv, a3, 0, 0, 0); break;
            }
        }
        #pragma unroll
        for (int kt = 0; kt < 16; ++kt) {
            const short8v bv = bP1[w][8 + kt][l];
            const short8v ah = hF[(kt * 2 + 0) * 64 + l];
            const short8v al = hF[(kt * 2 + 1) * 64 + l];
            switch (kt & 3) {
                case 0: a0 = MFMA(ah, bv, a0, 0, 0, 0); a0 = MFMA(al, bv, a0, 0, 0, 0); break;
                case 1: a1 = MFMA(ah, bv, a1, 0, 0, 0); a1 = MFMA(al, bv, a1, 0, 0, 0); break;
                case 2: a2 = MFMA(ah, bv, a2, 0, 0, 0); a2 = MFMA(al, bv, a2, 0, 0, 0); break;
                default: a3 = MFMA(ah, bv, a3, 0, 0, 0); a3 = MFMA(al, bv, a3, 0, 0, 0); break;
            }
        }
        float4v acc;
        acc[0] = a0[0] + a1[0] + a2[0] + a3[0];
        acc[1] = a0[1] + a1[1] + a2[1] + a3[1];
        acc[2] = a0[2] + a1[2] + a2[2] + a3[2];
        acc[3] = a0[3] + a1[3] + a2[3] + a3[3];
        #pragma unroll
        for (int r = 0; r < 4; ++r) {
            const int row = kg * 4 + r;
            const float v = acc[r] + bias1;
            const float sg = 1.f / (1.f + __expf(-v));
            if (isZ) {
                zFP[row * HH + colg1] = sg;
            } else {
                const float ho = hFP[row * HH + colg1];
                shpad[w * 256 + row * 16 + m_] = sg * ho;   // r*h staging
            }
        }
        if (isRWG) {
            __syncthreads();
            if (tid < 128) {   // pack r*h -> hi/lo A-fragments (2 k-tiles/WG)
                const int ktl = tid >> 6, ll = tid & 63;
                const int mm = ll & 15, kgg = ll >> 4;
                const int wsrc = ktl * 2 + (kgg >> 1), cb = (kgg & 1) * 8;
                short8v hi8, lo8;
                #pragma unroll
                for (int j = 0; j < 8; ++j) {
                    const float v = shpad[wsrc * 256 + mm * 16 + cb + j];
                    const unsigned short h = bf16_rne(v);
                    hi8[j] = (short)h;
                    lo8[j] = (short)bf16_rne(v - bf16_tof(h));
                }
                const int ktg = (s - 8) * 2 + ktl;
                rhF[(ktg * 2 + 0) * 64 + ll] = hi8;
                rhF[(ktg * 2 + 1) * 64 + ll] = lo8;
            }
        }
        __syncthreads();
        ++tgt;
        GROUP_BARRIER();

        // ---- P2: hc = tanh([x, r*h] @ Wh + b); h = (1-z)h + z*hc ----
        float4v b0 = {0.f,0.f,0.f,0.f}, b1 = b0;
        if (kh == 0) {
            #pragma unroll
            for (int kt = 0; kt < 8; ++kt) {
                const short8v av = xF[kt][l];
                const short8v bv = bP2[ntP2][kt][l];
                if (kt & 1) b1 = MFMA(av, bv, b1, 0, 0, 0);
                else        b0 = MFMA(av, bv, b0, 0, 0, 0);
            }
            #pragma unroll
            for (int kt = 8; kt < 12; ++kt) {
                const short8v bv = bP2[ntP2][kt][l];
                const short8v ah = rhF[((kt - 8) * 2 + 0) * 64 + l];
                const short8v al = rhF[((kt - 8) * 2 + 1) * 64 + l];
                if (kt & 1) { b1 = MFMA(ah, bv, b1, 0, 0, 0); b1 = MFMA(al, bv, b1, 0, 0, 0); }
                else        { b0 = MFMA(ah, bv, b0, 0, 0, 0); b0 = MFMA(al, bv, b0, 0, 0, 0); }
            }
        } else {
            #pragma unroll
            for (int kt = 12; kt < 24; ++kt) {
                const short8v bv = bP2[ntP2][kt][l];
                const short8v ah = rhF[((kt - 8) * 2 + 0) * 64 + l];
                const short8v al = rhF[((kt - 8) * 2 + 1) * 64 + l];
                if (kt & 1) { b1 = MFMA(ah, bv, b1, 0, 0, 0); b1 = MFMA(al, bv, b1, 0, 0, 0); }
                else        { b0 = MFMA(ah, bv, b0, 0, 0, 0); b0 = MFMA(al, bv, b0, 0, 0, 0); }
            }
        }
        acc[0] = b0[0] + b1[0]; acc[1] = b0[1] + b1[1];
        acc[2] = b0[2] + b1[2]; acc[3] = b0[3] + b1[3];
        if (kh == 1) {
            #pragma unroll
            for (int r = 0; r < 4; ++r)
                shpad[ntP2 * 256 + (kg * 4 + r) * 16 + m_] = acc[r];
        }
        __syncthreads();
        if (kh == 0) {
            #pragma unroll
            for (int r = 0; r < 4; ++r) {
                const int row = kg * 4 + r;
                const float v = acc[r] + shpad[ntP2 * 256 + row * 16 + m_] + bias2;
                const float hc = tanhf(v);
                const float zv = zFP[row * HH + colg2];
                const float ho = hFP[row * HH + colg2];
                const float hn = (1.f - zv) * ho + zv * hc;
                hFP[row * HH + colg2] = hn;
                out[(size_t)(g * 16 + row) * (TT * HH) + (size_t)t * HH + colg2] = hn;
                shpad[512 + row * 32 + ntP2 * 16 + m_] = hn;
            }
        }
        __syncthreads();
        if (tid < 64) {   // pack h_new -> hi/lo A-fragments (1 k-tile/WG: kt=s)
            const int mm = tid & 15, kgg = tid >> 4;
            short8v hi8, lo8;
            #pragma unroll
            for (int j = 0; j < 8; ++j) {
                const float v = shpad[512 + mm * 32 + kgg * 8 + j];
                const unsigned short h = bf16_rne(v);
                hi8[j] = (short)h;
                lo8[j] = (short)bf16_rne(v - bf16_tof(h));
            }
            hF[(s * 2 + 0) * 64 + tid] = hi8;
            hF[(s * 2 + 1) * 64 + tid] = lo8;
        }
        // stage x for t+1: global-load latency hides under the barrier spin
        if (t + 1 < TT) { STAGE_X(t + 1); }
        ++tgt;
        GROUP_BARRIER();
    }
#undef STAGE_X
#undef GROUP_BARRIER
}

// ---------------- fallback (round-3 kernel) if ws too small ----------------
#define NWG_FB 64
#define NTHR_FB 512
__global__ __launch_bounds__(NTHR_FB, 1) void gru_rowsplit(
    const float* __restrict__ x,
    const float* __restrict__ Wz, const float* __restrict__ bz,
    const float* __restrict__ Wr, const float* __restrict__ br,
    const float* __restrict__ Wh, const float* __restrict__ bh,
    float* __restrict__ out)
{
    __shared__ float comb_i [KK][2];
    __shared__ float comb2_i[KK][2];
    __shared__ float z_s[2][HH];
    __shared__ float red1[8][257];
    __shared__ float red2[24][129];

    const int tid  = threadIdx.x;
    const int row0 = blockIdx.x * 2;
    const int kh = tid >> 8;
    const int t1 = tid & 255;
    const int n1 = t1 * 4;
    const float* __restrict__ w1 =
        ((n1 < HH) ? (Wz + n1) : (Wr + (n1 - HH))) + (size_t)(kh * 384) * HH;
    const int kq = tid >> 7;
    const int t2 = tid & 127;
    const int n2 = t2 * 4;
    const float* __restrict__ w2 = Wh + n2 + (size_t)(kq * 192) * HH;

    float b1[4], b2[4];
    #pragma unroll
    for (int j = 0; j < 4; ++j) {
        b1[j] = (n1 + j < HH) ? bz[n1 + j] : br[n1 + j - HH];
        b2[j] = bh[n2 + j];
    }
    for (int idx = tid; idx < HH * 2; idx += NTHR_FB)
        comb_i[II + (idx >> 1)][idx & 1] = 0.f;
    __syncthreads();

    for (int t = 0; t < TT; ++t) {
        {
            const int r = tid >> 8, k = tid & 255;
            const float v = x[(size_t)(row0 + r) * (TT * II) + (size_t)t * II + k];
            comb_i [k][r] = v;
            comb2_i[k][r] = v;
        }
        __syncthreads();
        float a00=0,a01=0,a02=0,a03=0,a10=0,a11=0,a12=0,a13=0;
        {
            const int kb = kh * 384;
            #pragma unroll 8
            for (int k = 0; k < 384; ++k) {
                const float4 w = *(const float4*)(w1 + (size_t)k * HH);
                const float2 a = *(const float2*)&comb_i[kb + k][0];
                a00 += a.x*w.x; a01 += a.x*w.y; a02 += a.x*w.z; a03 += a.x*w.w;
                a10 += a.y*w.x; a11 += a.y*w.y; a12 += a.y*w.z; a13 += a.y*w.w;
            }
        }
        if (kh == 1) {
            red1[0][t1]=a00; red1[1][t1]=a01; red1[2][t1]=a02; red1[3][t1]=a03;
            red1[4][t1]=a10; red1[5][t1]=a11; red1[6][t1]=a12; red1[7][t1]=a13;
        }
        __syncthreads();
        if (kh == 0) {
            float accv[2][4] = {{a00,a01,a02,a03},{a10,a11,a12,a13}};
            #pragma unroll
            for (int r = 0; r < 2; ++r) {
                #pragma unroll
                for (int j = 0; j < 4; ++j) {
                    const int n = n1 + j;
                    const float v = accv[r][j] + red1[r*4+j][t1] + b1[j];
                    const float sg = 1.f / (1.f + __expf(-v));
                    if (n < HH) z_s[r][n] = sg;
                    else {
                        const int nh = n - HH;
                        comb2_i[II + nh][r] = sg * comb_i[II + nh][r];
                    }
                }
            }
        }
        __syncthreads();
        float c00=0,c01=0,c02=0,c03=0,c10=0,c11=0,c12=0,c13=0;
        {
            const int kb = kq * 192;
            #pragma unroll 8
            for (int k = 0; k < 192; ++k) {
                const float4 w = *(const float4*)(w2 + (size_t)k * HH);
                const float2 a = *(const float2*)&comb2_i[kb + k][0];
                c00 += a.x*w.x; c01 += a.x*w.y; c02 += a.x*w.z; c03 += a.x*w.w;
                c10 += a.y*w.x; c11 += a.y*w.y; c12 += a.y*w.z; c13 += a.y*w.w;
            }
        }
        if (kq > 0) {
            const int base = (kq - 1) * 8;
            red2[base+0][t2]=c00; red2[base+1][t2]=c01;
            red2[base+2][t2]=c02; red2[base+3][t2]=c03;
            red2[base+4][t2]=c10; red2[base+5][t2]=c11;
            red2[base+6][t2]=c12; red2[base+7][t2]=c13;
        }
        __syncthreads();
        if (kq == 0) {
            float accv[2][4] = {{c00,c01,c02,c03},{c10,c11,c12,c13}};
            #pragma unroll
            for (int r = 0; r < 2; ++r) {
                float hn4[4];
                #pragma unroll
                for (int j = 0; j < 4; ++j) {
                    const int n = n2 + j;
                    const int jj = r * 4 + j;
                    const float v = accv[r][j] + red2[jj][t2] + red2[8+jj][t2]
                                  + red2[16+jj][t2] + b2[j];
                    const float hc = tanhf(v);
                    const float zv = z_s[r][n];
                    const float ho = comb_i[II + n][r];
                    const float hn = (1.f - zv) * ho + zv * hc;
                    comb_i[II + n][r] = hn;
                    hn4[j] = hn;
                }
                *(float4*)&out[(size_t)(row0 + r) * (TT * HH) + (size_t)t * HH + n2] =
                    make_float4(hn4[0], hn4[1], hn4[2], hn4[3]);
            }
        }
        __syncthreads();
    }
}

extern "C" void kernel_launch(void* const* d_in, const int* in_sizes, int n_in,
                              void* d_out, int out_size, void* d_ws, size_t ws_size,
                              hipStream_t stream) {
    const float* x  = (const float*)d_in[0];
    const float* Wz = (const float*)d_in[1];
    const float* bz = (const float*)d_in[2];
    const float* Wr = (const float*)d_in[3];
    const float* br = (const float*)d_in[4];
    const float* Wh = (const float*)d_in[5];
    const float* bh = (const float*)d_in[6];
    float* out = (float*)d_out;

    if (ws_size < WS_NEED) {
        gru_rowsplit<<<NWG_FB, NTHR_FB, 0, stream>>>(x, Wz, bz, Wr, br, Wh, bh, out);
        return;
    }

    char* ws = (char*)d_ws;
    unsigned* bars = (unsigned*)(ws + BARS_OFF);
    short8v*  wB   = (short8v*)(ws + WFRAG_OFF);
    char*     gs   = ws + GS_OFF;

    hipMemsetAsync(bars, 0, BARS_SZ, stream);
    hipMemsetAsync(gs, 0, 8 * (size_t)GS_STRIDE, stream);   // zero h, frags, z
    repack_w<<<96, 256, 0, stream>>>(Wz, Wr, Wh, wB);
    gru_mfma<<<128, 256, 0, stream>>>(x, bz, br, bh, out, wB, gs, bars);
}

// Round 6
// 10564.874 us; speedup vs baseline: 1.6071x; 1.6071x over previous
//
#include <hip/hip_runtime.h>
#include <math.h>

#define BB 128
#define TT 1024
#define II 256
#define HH 512
#define KK 768

typedef __attribute__((ext_vector_type(8))) short short8v;
typedef __attribute__((ext_vector_type(4))) float float4v;
typedef __attribute__((ext_vector_type(2))) unsigned long long ulong2v;

// ---- workspace layout ----
#define BARS_OFF   0
#define BARS_SZ    16384                         // 128 WGs x 128B flag lines
#define WFRAG_OFF  BARS_SZ
#define WFRAG_SZ   (96 * 24 * 64 * 16)           // bf16 B-fragments
#define GS_OFF     (WFRAG_OFF + WFRAG_SZ)
#define GS_STRIDE  65536                         // per-group: hFrag 32KB + rhFrag 32KB
#define WS_NEED    ((size_t)GS_OFF + 8 * GS_STRIDE)

__device__ __forceinline__ unsigned short bf16_rne(float f) {
    unsigned u = __builtin_bit_cast(unsigned, f);
    unsigned r = u + 0x7FFFu + ((u >> 16) & 1u);
    return (unsigned short)(r >> 16);
}
__device__ __forceinline__ float bf16_tof(unsigned short h) {
    unsigned u = ((unsigned)h) << 16;
    return __builtin_bit_cast(float, u);
}
__device__ __forceinline__ void cp16(void* lds, const void* g) {
    __builtin_amdgcn_global_load_lds(
        (const __attribute__((address_space(1))) unsigned*)g,
        (__attribute__((address_space(3))) unsigned*)lds, 16, 0, 0);
}

#define MFMA __builtin_amdgcn_mfma_f32_16x16x32_bf16

// ---- one-time weight repack: fp32 [768][512] -> bf16 MFMA B-fragments ----
// frag(ntAll, kt): lane l, elem j -> W[kt*32 + (l>>4)*8 + j][n0 + (l&15)]
// ntAll 0..31: Wz, 32..63: Wr, 64..95: Wh
__global__ void repack_w(const float* __restrict__ Wz, const float* __restrict__ Wr,
                         const float* __restrict__ Wh, short8v* __restrict__ wB) {
    const int ntAll = blockIdx.x;
    const int w = threadIdx.x >> 6, l = threadIdx.x & 63;
    const float* W; int n0;
    if (ntAll < 32)      { W = Wz; n0 = ntAll * 16; }
    else if (ntAll < 64) { W = Wr; n0 = (ntAll - 32) * 16; }
    else                 { W = Wh; n0 = (ntAll - 64) * 16; }
    const int n = n0 + (l & 15);
    for (int kt = w; kt < 24; kt += 4) {
        const int k0 = kt * 32 + (l >> 4) * 8;
        short8v f;
        #pragma unroll
        for (int j = 0; j < 8; ++j)
            f[j] = (short)bf16_rne(W[(size_t)(k0 + j) * HH + n]);
        wB[((size_t)ntAll * 24 + kt) * 64 + l] = f;
    }
}

// ---- persistent MFMA GRU, fence-free cross-WG exchange ----
// 128 WGs x 256 thr; group g = bid&7 (16 batch rows), slice s = bid>>3 (cols 32s..32s+31).
// z, h-master fp32: WG-local LDS. Cross-WG: rh/h bf16 hi/lo frags via relaxed
// agent atomics (sc1, no cache-maintenance fences) + per-WG monotonic flags.
__global__ __launch_bounds__(256, 1) void gru_mfma(
    const float* __restrict__ x,
    const float* __restrict__ bz, const float* __restrict__ br,
    const float* __restrict__ bh,
    float* __restrict__ out,
    const short8v* __restrict__ wB,
    char* __restrict__ gsBase,
    unsigned* __restrict__ bars)
{
    __shared__ short8v bx1[4][8][64];   // 32KB P1 x-part weights (per wave)
    __shared__ short8v bx2[2][8][64];   // 16KB P2 x-part weights (per ntP2)
    __shared__ short8v xF[8][64];       //  8KB x_t A-frags
    __shared__ short8v hFL[32][64];     // 32KB staged h frags (hi/lo x 16 kt)
    __shared__ short8v rhFL[32][64];    // 32KB staged rh frags
    __shared__ float zA[16][33];        // z for local cols
    __shared__ float rhA[16][33];       // r*h staging (local cols)
    __shared__ float hA[16][33];        // h_new staging for pack
    __shared__ float hL[16][33];        // fp32 h master, local cols
    __shared__ float redA[2][16][17];   // P2 k-half reduction

    const int tid = threadIdx.x;
    const int w = tid >> 6, l = tid & 63;
    const int g = blockIdx.x & 7, s = blockIdx.x >> 3;
    const int m_ = l & 15, kg = l >> 4;
    const int ntP2 = w & 1;

    char* gs = gsBase + (size_t)g * GS_STRIDE;
    short8v* hFrag  = (short8v*)gs;              // 32 frags (ktl*2+part)
    short8v* rhFrag = hFrag + 32 * 64;
    unsigned* myflag = bars + (g * 16 + s) * 32;
    unsigned* gfbase = bars + g * 16 * 32;

    // ---- weight setup ----
    const int ct1 = s * 2 + ((w < 2) ? w : (w - 2));      // col-tile of z or r
    const int ntAll1 = (w < 2) ? ct1 : (32 + ct1);
    const short8v* wp1 = wB + (size_t)ntAll1 * 24 * 64;
    const short8v* wp2 = wB + (size_t)(64 + s * 2 + ntP2) * 24 * 64;

    for (int i = 0; i < 8; ++i) cp16(&bx1[w][i][0], wp1 + i * 64 + l);
    if (w < 2)
        for (int i = 0; i < 8; ++i) cp16(&bx2[w][i][0], wp2 + i * 64 + l);

    short8v wh1[16];                    // P1 h-part weights (regs)
    #pragma unroll
    for (int i = 0; i < 16; ++i) wh1[i] = wp1[(8 + i) * 64 + l];
    short8v wh2[10];                    // P2 rh-part weights (regs)
    #pragma unroll
    for (int i = 0; i < 10; ++i) {
        const int kt = (w < 2) ? (8 + (i < 6 ? i : 0)) : (14 + i);
        wh2[i] = wp2[kt * 64 + l];
    }

    const float bias1 = (w < 2) ? bz[ct1 * 16 + m_] : br[ct1 * 16 + m_];
    const float bias2 = bh[s * 32 + ntP2 * 16 + m_];

    for (int idx = tid; idx < 16 * 33; idx += 256) ((float*)hL)[idx] = 0.f;

#define STAGE_X(tt)                                                            \
    for (int slot = tid; slot < 512; slot += 256) {                            \
        const int kt = slot >> 6, ll = slot & 63;                              \
        const float* xp = x + (size_t)(g * 16 + (ll & 15)) * (TT * II)         \
                            + (size_t)(tt) * II + kt * 32 + (ll >> 4) * 8;     \
        const float4 v0 = *(const float4*)xp;                                  \
        const float4 v1 = *(const float4*)(xp + 4);                            \
        short8v f;                                                             \
        f[0] = (short)bf16_rne(v0.x); f[1] = (short)bf16_rne(v0.y);            \
        f[2] = (short)bf16_rne(v0.z); f[3] = (short)bf16_rne(v0.w);            \
        f[4] = (short)bf16_rne(v1.x); f[5] = (short)bf16_rne(v1.y);            \
        f[6] = (short)bf16_rne(v1.z); f[7] = (short)bf16_rne(v1.w);            \
        xF[kt][ll] = f;                                                        \
    }

#define POLL(TGT)                                                              \
    do {                                                                       \
        if (tid < 16) {                                                        \
            unsigned* fp = gfbase + tid * 32;                                  \
            while (__hip_atomic_load(fp, __ATOMIC_RELAXED,                     \
                                     __HIP_MEMORY_SCOPE_AGENT) < (TGT))        \
                __builtin_amdgcn_s_sleep(1);                                   \
        }                                                                      \
        asm volatile("" ::: "memory");                                         \
        __syncthreads();                                                       \
    } while (0)

#define STAGE_FRAGS(LARR, GPTR)                                                \
    _Pragma("unroll")                                                          \
    for (int it = 0; it < 8; ++it) {                                           \
        const int slot = tid + it * 256;                                       \
        const int f = slot >> 6, ll = slot & 63;                               \
        const unsigned long long* sp =                                         \
            (const unsigned long long*)(GPTR + (size_t)f * 64 + ll);           \
        ulong2v u;                                                             \
        u[0] = __hip_atomic_load(sp + 0, __ATOMIC_RELAXED,                     \
                                 __HIP_MEMORY_SCOPE_AGENT);                    \
        u[1] = __hip_atomic_load(sp + 1, __ATOMIC_RELAXED,                     \
                                 __HIP_MEMORY_SCOPE_AGENT);                    \
        LARR[f][ll] = __builtin_bit_cast(short8v, u);                          \
    }

#define PACK_STORE(SRC, DST)                                                   \
    if (tid < 128) {                                                           \
        const int part = tid >> 6, ll = tid & 63;                              \
        const int mm = ll & 15, j0 = (ll >> 4) * 8;                            \
        short8v fv;                                                            \
        _Pragma("unroll")                                                      \
        for (int j = 0; j < 8; ++j) {                                          \
            const float v = SRC[mm][j0 + j];                                   \
            const unsigned short hh = bf16_rne(v);                             \
            fv[j] = part ? (short)bf16_rne(v - bf16_tof(hh)) : (short)hh;      \
        }                                                                      \
        const ulong2v u = __builtin_bit_cast(ulong2v, fv);                     \
        unsigned long long* dp =                                               \
            (unsigned long long*)(DST + (size_t)(s * 2 + part) * 64 + ll);     \
        __hip_atomic_store(dp + 0, u[0], __ATOMIC_RELAXED,                     \
                           __HIP_MEMORY_SCOPE_AGENT);                          \
        __hip_atomic_store(dp + 1, u[1], __ATOMIC_RELAXED,                     \
                           __HIP_MEMORY_SCOPE_AGENT);                          \
    }

#define FLAG_STORE(VAL)                                                        \
    do {                                                                       \
        asm volatile("s_waitcnt vmcnt(0)" ::: "memory");                       \
        __syncthreads();                                                       \
        if (tid == 0)                                                          \
            __hip_atomic_store(myflag, (unsigned)(VAL), __ATOMIC_RELAXED,      \
                               __HIP_MEMORY_SCOPE_AGENT);                      \
    } while (0)

    STAGE_X(0);
    __syncthreads();   // drains cp16 vmcnt + xF/hL writes

    for (int t = 0; t < TT; ++t) {
        // ================= P1: [z|r] = sigmoid([x,h]W + b) =================
        float4v a0 = {0.f,0.f,0.f,0.f}, a1 = a0, a2 = a0, a3 = a0;
        #pragma unroll
        for (int kt = 0; kt < 8; ++kt) {        // x-part: no h dependency
            const short8v av = xF[kt][l];
            const short8v bv = bx1[w][kt][l];
            switch (kt & 3) {
                case 0: a0 = MFMA(av, bv, a0, 0, 0, 0); break;
                case 1: a1 = MFMA(av, bv, a1, 0, 0, 0); break;
                case 2: a2 = MFMA(av, bv, a2, 0, 0, 0); break;
                default: a3 = MFMA(av, bv, a3, 0, 0, 0); break;
            }
        }
        POLL(2u * t);                            // h(t-1) frags ready
        STAGE_FRAGS(hFL, hFrag);
        __syncthreads();
        #pragma unroll
        for (int ktl = 0; ktl < 16; ++ktl) {    // h-part
            const short8v bv = wh1[ktl];
            const short8v ah = hFL[2 * ktl][l];
            const short8v al = hFL[2 * ktl + 1][l];
            switch (ktl & 3) {
                case 0: a0 = MFMA(ah, bv, a0, 0, 0, 0); a0 = MFMA(al, bv, a0, 0, 0, 0); break;
                case 1: a1 = MFMA(ah, bv, a1, 0, 0, 0); a1 = MFMA(al, bv, a1, 0, 0, 0); break;
                case 2: a2 = MFMA(ah, bv, a2, 0, 0, 0); a2 = MFMA(al, bv, a2, 0, 0, 0); break;
                default: a3 = MFMA(ah, bv, a3, 0, 0, 0); a3 = MFMA(al, bv, a3, 0, 0, 0); break;
            }
        }
        #pragma unroll
        for (int r = 0; r < 4; ++r) {
            const int row = kg * 4 + r;
            const float v = (a0[r] + a1[r]) + (a2[r] + a3[r]) + bias1;
            const float sg = 1.f / (1.f + __expf(-v));
            if (w < 2) {
                zA[row][w * 16 + m_] = sg;
            } else {
                const int cl = (w - 2) * 16 + m_;
                rhA[row][cl] = sg * hL[row][cl];
            }
        }
        __syncthreads();
        PACK_STORE(rhA, rhFrag);
        FLAG_STORE(2u * t + 1u);

        // ================= P2: hc = tanh([x,rh]Wh + b); blend ==============
        float4v b0 = {0.f,0.f,0.f,0.f}, b1 = b0;
        if (w < 2) {                             // x-part before poll
            #pragma unroll
            for (int kt = 0; kt < 8; ++kt) {
                const short8v av = xF[kt][l];
                const short8v bv = bx2[w][kt][l];
                if (kt & 1) b1 = MFMA(av, bv, b1, 0, 0, 0);
                else        b0 = MFMA(av, bv, b0, 0, 0, 0);
            }
        }
        POLL(2u * t + 1u);                       // rh frags ready
        STAGE_FRAGS(rhFL, rhFrag);
        __syncthreads();
        if (w < 2) {                             // kh0: rh ktl 0..5
            #pragma unroll
            for (int i = 0; i < 6; ++i) {
                const short8v bv = wh2[i];
                const short8v ah = rhFL[2 * i][l];
                const short8v al = rhFL[2 * i + 1][l];
                if (i & 1) { b1 = MFMA(ah, bv, b1, 0, 0, 0); b1 = MFMA(al, bv, b1, 0, 0, 0); }
                else       { b0 = MFMA(ah, bv, b0, 0, 0, 0); b0 = MFMA(al, bv, b0, 0, 0, 0); }
            }
        } else {                                 // kh1: rh ktl 6..15
            #pragma unroll
            for (int i = 0; i < 10; ++i) {
                const short8v bv = wh2[i];
                const short8v ah = rhFL[2 * (6 + i)][l];
                const short8v al = rhFL[2 * (6 + i) + 1][l];
                if (i & 1) { b1 = MFMA(ah, bv, b1, 0, 0, 0); b1 = MFMA(al, bv, b1, 0, 0, 0); }
                else       { b0 = MFMA(ah, bv, b0, 0, 0, 0); b0 = MFMA(al, bv, b0, 0, 0, 0); }
            }
        }
        if (w >= 2) {
            #pragma unroll
            for (int r = 0; r < 4; ++r)
                redA[ntP2][kg * 4 + r][m_] = b0[r] + b1[r];
        }
        __syncthreads();
        if (w < 2) {
            #pragma unroll
            for (int r = 0; r < 4; ++r) {
                const int row = kg * 4 + r;
                const int cl = ntP2 * 16 + m_;
                const float v = b0[r] + b1[r] + redA[ntP2][row][m_] + bias2;
                const float hc = tanhf(v);
                const float zv = zA[row][cl];
                const float ho = hL[row][cl];
                const float hn = (1.f - zv) * ho + zv * hc;
                hL[row][cl] = hn;
                hA[row][cl] = hn;
                out[(size_t)(g * 16 + row) * (TT * HH) + (size_t)t * HH + s * 32 + cl] = hn;
            }
        }
        __syncthreads();
        PACK_STORE(hA, hFrag);
        FLAG_STORE(2u * t + 2u);
        if (t + 1 < TT) { STAGE_X(t + 1); }      // hides flag propagation
        __syncthreads();
    }
#undef STAGE_X
#undef POLL
#undef STAGE_FRAGS
#undef PACK_STORE
#undef FLAG_STORE
}

// ---------------- fallback (round-3 kernel) if ws too small ----------------
#define NWG_FB 64
#define NTHR_FB 512
__global__ __launch_bounds__(NTHR_FB, 1) void gru_rowsplit(
    const float* __restrict__ x,
    const float* __restrict__ Wz, const float* __restrict__ bz,
    const float* __restrict__ Wr, const float* __restrict__ br,
    const float* __restrict__ Wh, const float* __restrict__ bh,
    float* __restrict__ out)
{
    __shared__ float comb_i [KK][2];
    __shared__ float comb2_i[KK][2];
    __shared__ float z_s[2][HH];
    __shared__ float red1[8][257];
    __shared__ float red2[24][129];

    const int tid  = threadIdx.x;
    const int row0 = blockIdx.x * 2;
    const int kh = tid >> 8;
    const int t1 = tid & 255;
    const int n1 = t1 * 4;
    const float* __restrict__ w1 =
        ((n1 < HH) ? (Wz + n1) : (Wr + (n1 - HH))) + (size_t)(kh * 384) * HH;
    const int kq = tid >> 7;
    const int t2 = tid & 127;
    const int n2 = t2 * 4;
    const float* __restrict__ w2 = Wh + n2 + (size_t)(kq * 192) * HH;

    float b1[4], b2[4];
    #pragma unroll
    for (int j = 0; j < 4; ++j) {
        b1[j] = (n1 + j < HH) ? bz[n1 + j] : br[n1 + j - HH];
        b2[j] = bh[n2 + j];
    }
    for (int idx = tid; idx < HH * 2; idx += NTHR_FB)
        comb_i[II + (idx >> 1)][idx & 1] = 0.f;
    __syncthreads();

    for (int t = 0; t < TT; ++t) {
        {
            const int r = tid >> 8, k = tid & 255;
            const float v = x[(size_t)(row0 + r) * (TT * II) + (size_t)t * II + k];
            comb_i [k][r] = v;
            comb2_i[k][r] = v;
        }
        __syncthreads();
        float a00=0,a01=0,a02=0,a03=0,a10=0,a11=0,a12=0,a13=0;
        {
            const int kb = kh * 384;
            #pragma unroll 8
            for (int k = 0; k < 384; ++k) {
                const float4 w = *(const float4*)(w1 + (size_t)k * HH);
                const float2 a = *(const float2*)&comb_i[kb + k][0];
                a00 += a.x*w.x; a01 += a.x*w.y; a02 += a.x*w.z; a03 += a.x*w.w;
                a10 += a.y*w.x; a11 += a.y*w.y; a12 += a.y*w.z; a13 += a.y*w.w;
            }
        }
        if (kh == 1) {
            red1[0][t1]=a00; red1[1][t1]=a01; red1[2][t1]=a02; red1[3][t1]=a03;
            red1[4][t1]=a10; red1[5][t1]=a11; red1[6][t1]=a12; red1[7][t1]=a13;
        }
        __syncthreads();
        if (kh == 0) {
            float accv[2][4] = {{a00,a01,a02,a03},{a10,a11,a12,a13}};
            #pragma unroll
            for (int r = 0; r < 2; ++r) {
                #pragma unroll
                for (int j = 0; j < 4; ++j) {
                    const int n = n1 + j;
                    const float v = accv[r][j] + red1[r*4+j][t1] + b1[j];
                    const float sg = 1.f / (1.f + __expf(-v));
                    if (n < HH) z_s[r][n] = sg;
                    else {
                        const int nh = n - HH;
                        comb2_i[II + nh][r] = sg * comb_i[II + nh][r];
                    }
                }
            }
        }
        __syncthreads();
        float c00=0,c01=0,c02=0,c03=0,c10=0,c11=0,c12=0,c13=0;
        {
            const int kb = kq * 192;
            #pragma unroll 8
            for (int k = 0; k < 192; ++k) {
                const float4 w = *(const float4*)(w2 + (size_t)k * HH);
                const float2 a = *(const float2*)&comb2_i[kb + k][0];
                c00 += a.x*w.x; c01 += a.x*w.y; c02 += a.x*w.z; c03 += a.x*w.w;
                c10 += a.y*w.x; c11 += a.y*w.y; c12 += a.y*w.z; c13 += a.y*w.w;
            }
        }
        if (kq > 0) {
            const int base = (kq - 1) * 8;
            red2[base+0][t2]=c00; red2[base+1][t2]=c01;
            red2[base+2][t2]=c02; red2[base+3][t2]=c03;
            red2[base+4][t2]=c10; red2[base+5][t2]=c11;
            red2[base+6][t2]=c12; red2[base+7][t2]=c13;
        }
        __syncthreads();
        if (kq == 0) {
            float accv[2][4] = {{c00,c01,c02,c03},{c10,c11,c12,c13}};
            #pragma unroll
            for (int r = 0; r < 2; ++r) {
                float hn4[4];
                #pragma unroll
                for (int j = 0; j < 4; ++j) {
                    const int n = n2 + j;
                    const int jj = r * 4 + j;
                    const float v = accv[r][j] + red2[jj][t2] + red2[8+jj][t2]
                                  + red2[16+jj][t2] + b2[j];
                    const float hc = tanhf(v);
                    const float zv = z_s[r][n];
                    const float ho = comb_i[II + n][r];
                    const float hn = (1.f - zv) * ho + zv * hc;
                    comb_i[II + n][r] = hn;
                    hn4[j] = hn;
                }
                *(float4*)&out[(size_t)(row0 + r) * (TT * HH) + (size_t)t * HH + n2] =
                    make_float4(hn4[0], hn4[1], hn4[2], hn4[3]);
            }
        }
        __syncthreads();
    }
}

extern "C" void kernel_launch(void* const* d_in, const int* in_sizes, int n_in,
                              void* d_out, int out_size, void* d_ws, size_t ws_size,
                              hipStream_t stream) {
    const float* x  = (const float*)d_in[0];
    const float* Wz = (const float*)d_in[1];
    const float* bz = (const float*)d_in[2];
    const float* Wr = (const float*)d_in[3];
    const float* br = (const float*)d_in[4];
    const float* Wh = (const float*)d_in[5];
    const float* bh = (const float*)d_in[6];
    float* out = (float*)d_out;

    if (ws_size < WS_NEED) {
        gru_rowsplit<<<NWG_FB, NTHR_FB, 0, stream>>>(x, Wz, bz, Wr, br, Wh, bh, out);
        return;
    }

    char* ws = (char*)d_ws;
    unsigned* bars = (unsigned*)(ws + BARS_OFF);
    short8v*  wB   = (short8v*)(ws + WFRAG_OFF);
    char*     gs   = ws + GS_OFF;

    hipMemsetAsync(bars, 0, BARS_SZ, stream);
    hipMemsetAsync(gs, 0, 8 * (size_t)GS_STRIDE, stream);   // h0 = 0 frags
    repack_w<<<96, 256, 0, stream>>>(Wz, Wr, Wh, wB);
    gru_mfma<<<128, 256, 0, stream>>>(x, bz, br, bh, out, wB, gs, bars);
}

// Round 7
// 8406.786 us; speedup vs baseline: 2.0197x; 1.2567x over previous
//
#include <hip/hip_runtime.h>
#include <math.h>

#define BB 128
#define TT 1024
#define II 256
#define HH 512
#define KK 768

typedef __attribute__((ext_vector_type(8))) short short8v;
typedef __attribute__((ext_vector_type(4))) float float4v;
typedef __attribute__((ext_vector_type(2))) unsigned long long ulong2v;

// ---- workspace layout ----
#define BARS_OFF   0
#define BARS_SZ    32768                         // 8 grp x 16 WG x 64 uints (h@+0, rh@+32)
#define WFRAG_OFF  BARS_SZ
#define WFRAG_SZ   (96 * 24 * 64 * 16)           // bf16 MFMA B-fragments
#define GS_OFF     (WFRAG_OFF + WFRAG_SZ)
#define GS_STRIDE  65536                         // per-group: hFrag 32KB + rhFrag 32KB
#define WS_NEED    ((size_t)GS_OFF + 8 * GS_STRIDE)

__device__ __forceinline__ unsigned short bf16_rne(float f) {
    unsigned u = __builtin_bit_cast(unsigned, f);
    unsigned r = u + 0x7FFFu + ((u >> 16) & 1u);
    return (unsigned short)(r >> 16);
}
__device__ __forceinline__ float bf16_tof(unsigned short h) {
    unsigned u = ((unsigned)h) << 16;
    return __builtin_bit_cast(float, u);
}
__device__ __forceinline__ void cp16(void* lds, const void* g) {
    __builtin_amdgcn_global_load_lds(
        (const __attribute__((address_space(1))) unsigned*)g,
        (__attribute__((address_space(3))) unsigned*)lds, 16, 0, 0);
}
__device__ __forceinline__ void frag_store(short8v f, short8v* dst) {
    const ulong2v u = __builtin_bit_cast(ulong2v, f);
    unsigned long long* dp = (unsigned long long*)dst;
    __hip_atomic_store(dp + 0, u[0], __ATOMIC_RELAXED, __HIP_MEMORY_SCOPE_AGENT);
    __hip_atomic_store(dp + 1, u[1], __ATOMIC_RELAXED, __HIP_MEMORY_SCOPE_AGENT);
}
__device__ __forceinline__ short8v frag_load(const short8v* src) {
    const unsigned long long* sp = (const unsigned long long*)src;
    ulong2v u;
    u[0] = __hip_atomic_load(sp + 0, __ATOMIC_RELAXED, __HIP_MEMORY_SCOPE_AGENT);
    u[1] = __hip_atomic_load(sp + 1, __ATOMIC_RELAXED, __HIP_MEMORY_SCOPE_AGENT);
    return __builtin_bit_cast(short8v, u);
}

#define MFMA __builtin_amdgcn_mfma_f32_16x16x32_bf16

// ---- one-time weight repack: fp32 [768][512] -> bf16 MFMA B-fragments ----
// frag(ntAll, kt): lane l, elem j -> W[kt*32 + (l>>4)*8 + j][n0 + (l&15)]
// ntAll 0..31: Wz, 32..63: Wr, 64..95: Wh
__global__ void repack_w(const float* __restrict__ Wz, const float* __restrict__ Wr,
                         const float* __restrict__ Wh, short8v* __restrict__ wB) {
    const int ntAll = blockIdx.x;
    const int w = threadIdx.x >> 6, l = threadIdx.x & 63;
    const float* W; int n0;
    if (ntAll < 32)      { W = Wz; n0 = ntAll * 16; }
    else if (ntAll < 64) { W = Wr; n0 = (ntAll - 32) * 16; }
    else                 { W = Wh; n0 = (ntAll - 64) * 16; }
    const int n = n0 + (l & 15);
    for (int kt = w; kt < 24; kt += 4) {
        const int k0 = kt * 32 + (l >> 4) * 8;
        short8v f;
        #pragma unroll
        for (int j = 0; j < 8; ++j)
            f[j] = (short)bf16_rne(W[(size_t)(k0 + j) * HH + n]);
        wB[((size_t)ntAll * 24 + kt) * 64 + l] = f;
    }
}

// ---- persistent MFMA GRU, register-direct K-split exchange ----
// 128 WGs x 256 thr (4 waves). group g = bid&7 (16 batch rows), WG s = bid>>3
// owns cols [32s,32s+32) of z, r, hc. Cross-WG state: bf16 hi/lo A-frags via
// relaxed agent atomics; per-WG monotonic flags; per-wave polling; frags are
// consumed straight from registers (no LDS bounce).
__global__ __launch_bounds__(256, 1) void gru_mfma(
    const float* __restrict__ x,
    const float* __restrict__ bz, const float* __restrict__ br,
    const float* __restrict__ bh,
    float* __restrict__ out,
    const short8v* __restrict__ wB,
    char* __restrict__ gsBase,
    unsigned* __restrict__ bars)
{
    __shared__ short8v bx1[4][8][64];    // 32KB P1 x-part weights (wave's own tile)
    __shared__ short8v bx2[2][8][64];    // 16KB P2 x-part weights
    __shared__ short8v xF[8][64];        //  8KB x_t A-frags
    __shared__ float4v red1[4][4][64];   // 16KB P1 partials [tile][wave][lane]
    __shared__ float4v red2[2][4][64];   //  8KB P2 partials
    __shared__ float rhA[16][33];        // r*h staging (local cols)
    __shared__ float hL[16][33];         // fp32 h master (local cols), persistent

    const int tid = threadIdx.x;
    const int w = tid >> 6, l = tid & 63;
    const int g = blockIdx.x & 7, s = blockIdx.x >> 3;
    const int m_ = l & 15, kg = l >> 4;

    char* gs = gsBase + (size_t)g * GS_STRIDE;
    short8v* hFrag  = (short8v*)gs;                  // [16 kt][2 hi/lo][64]
    short8v* rhFrag = hFrag + 16 * 2 * 64;
    unsigned* flagBase = bars + (size_t)g * 16 * 64; // +s*64; h@+0, rh@+32

    // ---- weight setup ----
    const int ownNt = (w < 2) ? (2 * s + w) : (32 + 2 * s + (w - 2));
    for (int i = 0; i < 8; ++i)
        cp16(&bx1[w][i][0], wB + ((size_t)ownNt * 24 + i) * 64 + l);
    if (w < 2)
        for (int i = 0; i < 8; ++i)
            cp16(&bx2[w][i][0], wB + ((size_t)(64 + 2 * s + w) * 24 + i) * 64 + l);

    short8v wh1[4][4];                   // P1 h-part: [tile][k-quarter slot]
    #pragma unroll
    for (int T = 0; T < 4; ++T) {
        const int nt = (T < 2) ? (2 * s + T) : (32 + 2 * s + (T - 2));
        #pragma unroll
        for (int q = 0; q < 4; ++q)
            wh1[T][q] = wB[((size_t)nt * 24 + 8 + 4 * w + q) * 64 + l];
    }
    short8v wh2[2][4];                   // P2 rh-part: [hc tile][k-quarter slot]
    #pragma unroll
    for (int n2 = 0; n2 < 2; ++n2) {
        #pragma unroll
        for (int q = 0; q < 4; ++q)
            wh2[n2][q] = wB[((size_t)(64 + 2 * s + n2) * 24 + 8 + 4 * w + q) * 64 + l];
    }

    const float bias1 = (w < 2) ? bz[s * 32 + w * 16 + m_]
                                : br[s * 32 + (w - 2) * 16 + m_];
    const float bias2 = (w < 2) ? bh[s * 32 + w * 16 + m_] : 0.f;

    for (int idx = tid; idx < 16 * 33; idx += 256) ((float*)hL)[idx] = 0.f;

    // ---- prologue x stage (t = 0), all threads ----
    #pragma unroll
    for (int i2 = 0; i2 < 2; ++i2) {
        const int slot = tid + i2 * 256;
        const int kt = slot >> 6, ll = slot & 63;
        const float* xp = x + (size_t)(g * 16 + (ll & 15)) * (TT * II)
                            + kt * 32 + (ll >> 4) * 8;
        const float4 v0 = *(const float4*)xp;
        const float4 v1 = *(const float4*)(xp + 4);
        short8v f;
        f[0] = (short)bf16_rne(v0.x); f[1] = (short)bf16_rne(v0.y);
        f[2] = (short)bf16_rne(v0.z); f[3] = (short)bf16_rne(v0.w);
        f[4] = (short)bf16_rne(v1.x); f[5] = (short)bf16_rne(v1.y);
        f[6] = (short)bf16_rne(v1.z); f[7] = (short)bf16_rne(v1.w);
        xF[kt][ll] = f;
    }
    __syncthreads();   // drains cp16 vmcnt + xF/hL writes

    float4 xb[16];     // wave3's x(t+1) prefetch registers

    for (int t = 0; t < TT; ++t) {
        // ===== phase 1: P1 x-part MFMA (own tile; independent of h) =====
        float4v ax0 = {0.f, 0.f, 0.f, 0.f}, ax1 = ax0;
        #pragma unroll
        for (int kt = 0; kt < 8; kt += 2) {
            ax0 = MFMA(xF[kt][l],     bx1[w][kt][l],     ax0, 0, 0, 0);
            ax1 = MFMA(xF[kt + 1][l], bx1[w][kt + 1][l], ax1, 0, 0, 0);
        }

        // ===== phase 2: poll h(t-1), load own k-quarter, MFMA all 4 tiles =====
        if (l < 16) {
            const unsigned* fp = flagBase + l * 64;
            while (__hip_atomic_load(fp, __ATOMIC_RELAXED,
                                     __HIP_MEMORY_SCOPE_AGENT) < (unsigned)t)
                __builtin_amdgcn_s_sleep(1);
        }
        asm volatile("" ::: "memory");
        short8v hf[8];
        #pragma unroll
        for (int i = 0; i < 8; ++i)
            hf[i] = frag_load(hFrag + ((4 * w + (i >> 1)) * 2 + (i & 1)) * 64 + l);
        float4v h0 = {0.f,0.f,0.f,0.f}, h1 = h0, h2 = h0, h3 = h0;
        #pragma unroll
        for (int q = 0; q < 4; ++q) {
            h0 = MFMA(hf[2*q], wh1[0][q], h0, 0, 0, 0);
            h0 = MFMA(hf[2*q+1], wh1[0][q], h0, 0, 0, 0);
            h1 = MFMA(hf[2*q], wh1[1][q], h1, 0, 0, 0);
            h1 = MFMA(hf[2*q+1], wh1[1][q], h1, 0, 0, 0);
            h2 = MFMA(hf[2*q], wh1[2][q], h2, 0, 0, 0);
            h2 = MFMA(hf[2*q+1], wh1[2][q], h2, 0, 0, 0);
            h3 = MFMA(hf[2*q], wh1[3][q], h3, 0, 0, 0);
            h3 = MFMA(hf[2*q+1], wh1[3][q], h3, 0, 0, 0);
        }

        // ===== phase 3: reduce quarters; wave3 issues x(t+1) loads =====
        red1[0][w][l] = h0; red1[1][w][l] = h1;
        red1[2][w][l] = h2; red1[3][w][l] = h3;
        if (w == 3 && t + 1 < TT) {
            #pragma unroll
            for (int i = 0; i < 8; ++i) {
                const float* xp = x + (size_t)(g * 16 + m_) * (TT * II)
                                    + (size_t)(t + 1) * II + i * 32 + kg * 8;
                xb[2 * i]     = *(const float4*)xp;
                xb[2 * i + 1] = *(const float4*)(xp + 4);
            }
        }
        __syncthreads();   // S1
        float4v s1 = ax0 + ax1 + red1[w][0][l] + red1[w][1][l]
                             + red1[w][2][l] + red1[w][3][l];
        float zreg[4];
        #pragma unroll
        for (int r = 0; r < 4; ++r) {
            const float sg = 1.f / (1.f + __expf(-(s1[r] + bias1)));
            if (w < 2) zreg[r] = sg;
            else rhA[kg * 4 + r][(w - 2) * 16 + m_] =
                     sg * hL[kg * 4 + r][(w - 2) * 16 + m_];
        }
        __syncthreads();   // S2

        // ===== phase 4: wave2 packs+publishes rh; waves 0,1 P2 x-part =====
        if (w == 2) {
            short8v hi8, lo8;
            #pragma unroll
            for (int j = 0; j < 8; ++j) {
                const float v = rhA[m_][kg * 8 + j];
                const unsigned short hh = bf16_rne(v);
                hi8[j] = (short)hh;
                lo8[j] = (short)bf16_rne(v - bf16_tof(hh));
            }
            frag_store(hi8, rhFrag + (s * 2 + 0) * 64 + l);
            frag_store(lo8, rhFrag + (s * 2 + 1) * 64 + l);
            asm volatile("s_waitcnt vmcnt(0)" ::: "memory");
            if (l == 0)
                __hip_atomic_store(flagBase + s * 64 + 32, (unsigned)(t + 1),
                                   __ATOMIC_RELAXED, __HIP_MEMORY_SCOPE_AGENT);
        }
        float4v cx0 = {0.f,0.f,0.f,0.f}, cx1 = cx0;
        if (w < 2) {
            #pragma unroll
            for (int kt = 0; kt < 8; kt += 2) {
                cx0 = MFMA(xF[kt][l],     bx2[w][kt][l],     cx0, 0, 0, 0);
                cx1 = MFMA(xF[kt + 1][l], bx2[w][kt + 1][l], cx1, 0, 0, 0);
            }
        }

        // ===== phase 5: poll rh, load own k-quarter, MFMA both hc tiles =====
        if (l < 16) {
            const unsigned* fp = flagBase + l * 64 + 32;
            while (__hip_atomic_load(fp, __ATOMIC_RELAXED,
                                     __HIP_MEMORY_SCOPE_AGENT) < (unsigned)(t + 1))
                __builtin_amdgcn_s_sleep(1);
        }
        asm volatile("" ::: "memory");
        short8v rf[8];
        #pragma unroll
        for (int i = 0; i < 8; ++i)
            rf[i] = frag_load(rhFrag + ((4 * w + (i >> 1)) * 2 + (i & 1)) * 64 + l);
        float4v c0 = {0.f,0.f,0.f,0.f}, c1 = c0;
        #pragma unroll
        for (int q = 0; q < 4; ++q) {
            c0 = MFMA(rf[2*q], wh2[0][q], c0, 0, 0, 0);
            c0 = MFMA(rf[2*q+1], wh2[0][q], c0, 0, 0, 0);
            c1 = MFMA(rf[2*q], wh2[1][q], c1, 0, 0, 0);
            c1 = MFMA(rf[2*q+1], wh2[1][q], c1, 0, 0, 0);
        }
        red2[0][w][l] = c0; red2[1][w][l] = c1;
        __syncthreads();   // S3

        // ===== phase 6: blend (waves 0,1); wave3 writes xF(t+1) =====
        if (w < 2) {
            float4v s2 = cx0 + cx1 + red2[w][0][l] + red2[w][1][l]
                               + red2[w][2][l] + red2[w][3][l];
            #pragma unroll
            for (int r = 0; r < 4; ++r) {
                const int row = kg * 4 + r;
                const int cl = w * 16 + m_;
                const float hc = tanhf(s2[r] + bias2);
                const float ho = hL[row][cl];
                const float hn = (1.f - zreg[r]) * ho + zreg[r] * hc;
                hL[row][cl] = hn;
                out[(size_t)(g * 16 + row) * (TT * HH) + (size_t)t * HH
                    + s * 32 + cl] = hn;
            }
        } else if (w == 3 && t + 1 < TT) {
            #pragma unroll
            for (int i = 0; i < 8; ++i) {
                const float4 v0 = xb[2 * i], v1 = xb[2 * i + 1];
                short8v f;
                f[0] = (short)bf16_rne(v0.x); f[1] = (short)bf16_rne(v0.y);
                f[2] = (short)bf16_rne(v0.z); f[3] = (short)bf16_rne(v0.w);
                f[4] = (short)bf16_rne(v1.x); f[5] = (short)bf16_rne(v1.y);
                f[6] = (short)bf16_rne(v1.z); f[7] = (short)bf16_rne(v1.w);
                xF[i][l] = f;
            }
        }
        __syncthreads();   // S4

        // ===== phase 7: wave0 packs+publishes h(t) =====
        if (w == 0) {
            short8v hi8, lo8;
            #pragma unroll
            for (int j = 0; j < 8; ++j) {
                const float v = hL[m_][kg * 8 + j];
                const unsigned short hh = bf16_rne(v);
                hi8[j] = (short)hh;
                lo8[j] = (short)bf16_rne(v - bf16_tof(hh));
            }
            frag_store(hi8, hFrag + (s * 2 + 0) * 64 + l);
            frag_store(lo8, hFrag + (s * 2 + 1) * 64 + l);
            asm volatile("s_waitcnt vmcnt(0)" ::: "memory");
            if (l == 0)
                __hip_atomic_store(flagBase + s * 64, (unsigned)(t + 1),
                                   __ATOMIC_RELAXED, __HIP_MEMORY_SCOPE_AGENT);
        }
    }
}

// ---------------- fallback (round-3 kernel) if ws too small ----------------
#define NWG_FB 64
#define NTHR_FB 512
__global__ __launch_bounds__(NTHR_FB, 1) void gru_rowsplit(
    const float* __restrict__ x,
    const float* __restrict__ Wz, const float* __restrict__ bz,
    const float* __restrict__ Wr, const float* __restrict__ br,
    const float* __restrict__ Wh, const float* __restrict__ bh,
    float* __restrict__ out)
{
    __shared__ float comb_i [KK][2];
    __shared__ float comb2_i[KK][2];
    __shared__ float z_s[2][HH];
    __shared__ float red1[8][257];
    __shared__ float red2[24][129];

    const int tid  = threadIdx.x;
    const int row0 = blockIdx.x * 2;
    const int kh = tid >> 8;
    const int t1 = tid & 255;
    const int n1 = t1 * 4;
    const float* __restrict__ w1 =
        ((n1 < HH) ? (Wz + n1) : (Wr + (n1 - HH))) + (size_t)(kh * 384) * HH;
    const int kq = tid >> 7;
    const int t2 = tid & 127;
    const int n2 = t2 * 4;
    const float* __restrict__ w2 = Wh + n2 + (size_t)(kq * 192) * HH;

    float b1[4], b2[4];
    #pragma unroll
    for (int j = 0; j < 4; ++j) {
        b1[j] = (n1 + j < HH) ? bz[n1 + j] : br[n1 + j - HH];
        b2[j] = bh[n2 + j];
    }
    for (int idx = tid; idx < HH * 2; idx += NTHR_FB)
        comb_i[II + (idx >> 1)][idx & 1] = 0.f;
    __syncthreads();

    for (int t = 0; t < TT; ++t) {
        {
            const int r = tid >> 8, k = tid & 255;
            const float v = x[(size_t)(row0 + r) * (TT * II) + (size_t)t * II + k];
            comb_i [k][r] = v;
            comb2_i[k][r] = v;
        }
        __syncthreads();
        float a00=0,a01=0,a02=0,a03=0,a10=0,a11=0,a12=0,a13=0;
        {
            const int kb = kh * 384;
            #pragma unroll 8
            for (int k = 0; k < 384; ++k) {
                const float4 w = *(const float4*)(w1 + (size_t)k * HH);
                const float2 a = *(const float2*)&comb_i[kb + k][0];
                a00 += a.x*w.x; a01 += a.x*w.y; a02 += a.x*w.z; a03 += a.x*w.w;
                a10 += a.y*w.x; a11 += a.y*w.y; a12 += a.y*w.z; a13 += a.y*w.w;
            }
        }
        if (kh == 1) {
            red1[0][t1]=a00; red1[1][t1]=a01; red1[2][t1]=a02; red1[3][t1]=a03;
            red1[4][t1]=a10; red1[5][t1]=a11; red1[6][t1]=a12; red1[7][t1]=a13;
        }
        __syncthreads();
        if (kh == 0) {
            float accv[2][4] = {{a00,a01,a02,a03},{a10,a11,a12,a13}};
            #pragma unroll
            for (int r = 0; r < 2; ++r) {
                #pragma unroll
                for (int j = 0; j < 4; ++j) {
                    const int n = n1 + j;
                    const float v = accv[r][j] + red1[r*4+j][t1] + b1[j];
                    const float sg = 1.f / (1.f + __expf(-v));
                    if (n < HH) z_s[r][n] = sg;
                    else {
                        const int nh = n - HH;
                        comb2_i[II + nh][r] = sg * comb_i[II + nh][r];
                    }
                }
            }
        }
        __syncthreads();
        float c00=0,c01=0,c02=0,c03=0,c10=0,c11=0,c12=0,c13=0;
        {
            const int kb = kq * 192;
            #pragma unroll 8
            for (int k = 0; k < 192; ++k) {
                const float4 w = *(const float4*)(w2 + (size_t)k * HH);
                const float2 a = *(const float2*)&comb2_i[kb + k][0];
                c00 += a.x*w.x; c01 += a.x*w.y; c02 += a.x*w.z; c03 += a.x*w.w;
                c10 += a.y*w.x; c11 += a.y*w.y; c12 += a.y*w.z; c13 += a.y*w.w;
            }
        }
        if (kq > 0) {
            const int base = (kq - 1) * 8;
            red2[base+0][t2]=c00; red2[base+1][t2]=c01;
            red2[base+2][t2]=c02; red2[base+3][t2]=c03;
            red2[base+4][t2]=c10; red2[base+5][t2]=c11;
            red2[base+6][t2]=c12; red2[base+7][t2]=c13;
        }
        __syncthreads();
        if (kq == 0) {
            float accv[2][4] = {{c00,c01,c02,c03},{c10,c11,c12,c13}};
            #pragma unroll
            for (int r = 0; r < 2; ++r) {
                float hn4[4];
                #pragma unroll
                for (int j = 0; j < 4; ++j) {
                    const int n = n2 + j;
                    const int jj = r * 4 + j;
                    const float v = accv[r][j] + red2[jj][t2] + red2[8+jj][t2]
                                  + red2[16+jj][t2] + b2[j];
                    const float hc = tanhf(v);
                    const float zv = z_s[r][n];
                    const float ho = comb_i[II + n][r];
                    const float hn = (1.f - zv) * ho + zv * hc;
                    comb_i[II + n][r] = hn;
                    hn4[j] = hn;
                }
                *(float4*)&out[(size_t)(row0 + r) * (TT * HH) + (size_t)t * HH + n2] =
                    make_float4(hn4[0], hn4[1], hn4[2], hn4[3]);
            }
        }
        __syncthreads();
    }
}

extern "C" void kernel_launch(void* const* d_in, const int* in_sizes, int n_in,
                              void* d_out, int out_size, void* d_ws, size_t ws_size,
                              hipStream_t stream) {
    const float* x  = (const float*)d_in[0];
    const float* Wz = (const float*)d_in[1];
    const float* bz = (const float*)d_in[2];
    const float* Wr = (const float*)d_in[3];
    const float* br = (const float*)d_in[4];
    const float* Wh = (const float*)d_in[5];
    const float* bh = (const float*)d_in[6];
    float* out = (float*)d_out;

    if (ws_size < WS_NEED) {
        gru_rowsplit<<<NWG_FB, NTHR_FB, 0, stream>>>(x, Wz, bz, Wr, br, Wh, bh, out);
        return;
    }

    char* ws = (char*)d_ws;
    unsigned* bars = (unsigned*)(ws + BARS_OFF);
    short8v*  wB   = (short8v*)(ws + WFRAG_OFF);
    char*     gs   = ws + GS_OFF;

    hipMemsetAsync(bars, 0, BARS_SZ, stream);
    hipMemsetAsync(gs, 0, 8 * (size_t)GS_STRIDE, stream);   // h0 = 0 frags
    repack_w<<<96, 256, 0, stream>>>(Wz, Wr, Wh, wB);
    gru_mfma<<<128, 256, 0, stream>>>(x, bz, br, bh, out, wB, gs, bars);
}

// Round 8
// 4530.526 us; speedup vs baseline: 3.7477x; 1.8556x over previous
//
#include <hip/hip_runtime.h>
#include <math.h>

#define BB 128
#define TT 1024
#define II 256
#define HH 512
#define KK 768

typedef __attribute__((ext_vector_type(8))) short short8v;
typedef __attribute__((ext_vector_type(4))) float float4v;
typedef __attribute__((ext_vector_type(4))) unsigned int uint4v;

// ---- workspace layout ----
#define BARS_OFF   0
#define BARS_SZ    32768                         // 8 grp x 16 WG x 64 uints (h@+0, rh@+32)
#define WFRAG_OFF  BARS_SZ
#define WFRAG_SZ   (96 * 24 * 64 * 16)           // bf16 MFMA B-fragments
#define GS_OFF     (WFRAG_OFF + WFRAG_SZ)
#define GS_STRIDE  65536                         // per-group: hFrag 16KB + rhFrag 16KB
#define WS_NEED    ((size_t)GS_OFF + 8 * GS_STRIDE)

#define NT_MAIN 320                              // 4 compute waves + 1 stager wave

__device__ __forceinline__ unsigned short bf16_rne(float f) {
    unsigned u = __builtin_bit_cast(unsigned, f);
    unsigned r = u + 0x7FFFu + ((u >> 16) & 1u);
    return (unsigned short)(r >> 16);
}
__device__ __forceinline__ void cp16(void* lds, const void* g) {
    __builtin_amdgcn_global_load_lds(
        (const __attribute__((address_space(1))) unsigned*)g,
        (__attribute__((address_space(3))) unsigned*)lds, 16, 0, 0);
}

#define MFMA __builtin_amdgcn_mfma_f32_16x16x32_bf16

// ---- one-time weight repack: fp32 [768][512] -> bf16 MFMA B-fragments ----
// frag(ntAll, kt): lane l, elem j -> W[kt*32 + (l>>4)*8 + j][n0 + (l&15)]
// ntAll 0..31: Wz, 32..63: Wr, 64..95: Wh
__global__ void repack_w(const float* __restrict__ Wz, const float* __restrict__ Wr,
                         const float* __restrict__ Wh, short8v* __restrict__ wB) {
    const int ntAll = blockIdx.x;
    const int w = threadIdx.x >> 6, l = threadIdx.x & 63;
    const float* W; int n0;
    if (ntAll < 32)      { W = Wz; n0 = ntAll * 16; }
    else if (ntAll < 64) { W = Wr; n0 = (ntAll - 32) * 16; }
    else                 { W = Wh; n0 = (ntAll - 64) * 16; }
    const int n = n0 + (l & 15);
    for (int kt = w; kt < 24; kt += 4) {
        const int k0 = kt * 32 + (l >> 4) * 8;
        short8v f;
        #pragma unroll
        for (int j = 0; j < 8; ++j)
            f[j] = (short)bf16_rne(W[(size_t)(k0 + j) * HH + n]);
        wB[((size_t)ntAll * 24 + kt) * 64 + l] = f;
    }
}

// ---- persistent MFMA GRU ----
// 128 WGs x 320 thr (4 compute waves + stager wave4). group g = bid&7 (16 rows),
// WG s = bid>>3 owns cols [32s,32s+32). Cross-WG state: bf16 A-frags via plain
// sc1 (agent-coherent) dwordx4 loads/stores; per-WG monotonic flags; each wave
// polls only its 4 k-quarter producers. Wave4: x(t+1) prefetch + h publish
// (per-wave vmcnt keeps HBM latency off the compute waves' frag waits).
__global__ __launch_bounds__(NT_MAIN, 1) void gru_mfma(
    const float* __restrict__ x,
    const float* __restrict__ bz, const float* __restrict__ br,
    const float* __restrict__ bh,
    float* __restrict__ out,
    const short8v* __restrict__ wB,
    char* __restrict__ gsBase,
    unsigned* __restrict__ bars)
{
    __shared__ short8v bx1[4][8][64];    // 32KB P1 x-part weights (wave's tile)
    __shared__ short8v bx2[2][8][64];    // 16KB P2 x-part weights
    __shared__ short8v xF[8][64];        //  8KB x_t A-frags
    __shared__ float4v red1[4][4][64];   // 16KB P1 partials [tile][wave][lane]
    __shared__ float4v red2[2][4][64];   //  8KB P2 partials
    __shared__ float rhA[16][33];        // r*h staging (local cols)
    __shared__ float hL[16][33];         // fp32 h master (local cols), persistent

    const int tid = threadIdx.x;
    const int w = tid >> 6, l = tid & 63;
    const int g = blockIdx.x & 7, s = blockIdx.x >> 3;
    const int m_ = l & 15, kg = l >> 4;

    char* gs = gsBase + (size_t)g * GS_STRIDE;
    short8v* hFrag  = (short8v*)gs;                  // 16 frags x 1KB
    short8v* rhFrag = hFrag + 16 * 64;
    unsigned* flagBase = bars + (size_t)g * 16 * 64; // +s*64; h@+0, rh@+32

    // ---- weight setup (compute waves only) ----
    short8v wh1[4][4];   // P1 h-part  [out tile][k-slot in this wave's quarter]
    short8v wh2[2][4];   // P2 rh-part [hc tile][k-slot]
    if (w < 4) {
        const int ownNt = (w < 2) ? (2 * s + w) : (32 + 2 * s + (w - 2));
        for (int i = 0; i < 8; ++i)
            cp16(&bx1[w][i][0], wB + ((size_t)ownNt * 24 + i) * 64 + l);
        if (w < 2)
            for (int i = 0; i < 8; ++i)
                cp16(&bx2[w][i][0], wB + ((size_t)(64 + 2 * s + w) * 24 + i) * 64 + l);
        #pragma unroll
        for (int T = 0; T < 4; ++T) {
            const int nt = (T < 2) ? (2 * s + T) : (32 + 2 * s + (T - 2));
            #pragma unroll
            for (int q = 0; q < 4; ++q)
                wh1[T][q] = wB[((size_t)nt * 24 + 8 + 4 * w + q) * 64 + l];
        }
        #pragma unroll
        for (int n2 = 0; n2 < 2; ++n2)
            #pragma unroll
            for (int q = 0; q < 4; ++q)
                wh2[n2][q] = wB[((size_t)(64 + 2 * s + n2) * 24 + 8 + 4 * w + q) * 64 + l];
    }
    const float bias1 = (w < 2) ? bz[s * 32 + w * 16 + m_]
                    : (w < 4)  ? br[s * 32 + (w - 2) * 16 + m_] : 0.f;
    const float bias2 = (w < 2) ? bh[s * 32 + w * 16 + m_] : 0.f;

    for (int idx = tid; idx < 16 * 33; idx += NT_MAIN) ((float*)hL)[idx] = 0.f;

    // ---- prologue: stage x(0) (all threads) ----
    for (int slot = tid; slot < 512; slot += NT_MAIN) {
        const int kt = slot >> 6, ll = slot & 63;
        const float* xp = x + (size_t)(g * 16 + (ll & 15)) * (TT * II)
                            + kt * 32 + (ll >> 4) * 8;
        const float4 v0 = *(const float4*)xp;
        const float4 v1 = *(const float4*)(xp + 4);
        short8v f;
        f[0] = (short)bf16_rne(v0.x); f[1] = (short)bf16_rne(v0.y);
        f[2] = (short)bf16_rne(v0.z); f[3] = (short)bf16_rne(v0.w);
        f[4] = (short)bf16_rne(v1.x); f[5] = (short)bf16_rne(v1.y);
        f[6] = (short)bf16_rne(v1.z); f[7] = (short)bf16_rne(v1.w);
        xF[kt][ll] = f;
    }
    __syncthreads();   // drains cp16 vmcnt + xF/hL writes

    float4 xv[16];     // wave4's x(t+1) prefetch registers

    for (int t = 0; t < TT; ++t) {
        // ===== phase 1: compute waves: P1 x-part; wave4: issue x(t+1) loads =====
        float4v ax0 = {0.f, 0.f, 0.f, 0.f}, ax1 = ax0;
        if (w < 4) {
            #pragma unroll
            for (int kt = 0; kt < 8; kt += 2) {
                ax0 = MFMA(xF[kt][l],     bx1[w][kt][l],     ax0, 0, 0, 0);
                ax1 = MFMA(xF[kt + 1][l], bx1[w][kt + 1][l], ax1, 0, 0, 0);
            }
        } else if (t + 1 < TT) {
            #pragma unroll
            for (int i = 0; i < 8; ++i) {
                const float* xp = x + (size_t)(g * 16 + m_) * (TT * II)
                                    + (size_t)(t + 1) * II + i * 32 + kg * 8;
                xv[2 * i]     = *(const float4*)xp;
                xv[2 * i + 1] = *(const float4*)(xp + 4);
            }
        }

        // ===== phase 2: poll own 4 h-producers, load frags, MFMA h-part =====
        short8v hf0, hf1, hf2, hf3;
        if (w < 4) {
            if (l < 4) {
                const unsigned* fp = flagBase + (4 * w + l) * 64;
                while (__hip_atomic_load(fp, __ATOMIC_RELAXED,
                                         __HIP_MEMORY_SCOPE_AGENT) < (unsigned)t)
                    __builtin_amdgcn_s_sleep(1);
            }
            uint4v u0, u1, u2, u3;
            const short8v* hp = hFrag + (size_t)(4 * w) * 64 + l;
            asm volatile("global_load_dwordx4 %0, %1, off sc1" : "=v"(u0) : "v"(hp)       : "memory");
            asm volatile("global_load_dwordx4 %0, %1, off sc1" : "=v"(u1) : "v"(hp +  64) : "memory");
            asm volatile("global_load_dwordx4 %0, %1, off sc1" : "=v"(u2) : "v"(hp + 128) : "memory");
            asm volatile("global_load_dwordx4 %0, %1, off sc1" : "=v"(u3) : "v"(hp + 192) : "memory");
            asm volatile("s_waitcnt vmcnt(0)" ::: "memory");
            __builtin_amdgcn_sched_barrier(0);
            hf0 = __builtin_bit_cast(short8v, u0);
            hf1 = __builtin_bit_cast(short8v, u1);
            hf2 = __builtin_bit_cast(short8v, u2);
            hf3 = __builtin_bit_cast(short8v, u3);
            float4v h0 = {0.f,0.f,0.f,0.f}, h1 = h0, h2 = h0, h3 = h0;
            #pragma unroll
            for (int q = 0; q < 4; ++q) {
                const short8v a = (q == 0) ? hf0 : (q == 1) ? hf1 : (q == 2) ? hf2 : hf3;
                h0 = MFMA(a, wh1[0][q], h0, 0, 0, 0);
                h1 = MFMA(a, wh1[1][q], h1, 0, 0, 0);
                h2 = MFMA(a, wh1[2][q], h2, 0, 0, 0);
                h3 = MFMA(a, wh1[3][q], h3, 0, 0, 0);
            }
            red1[0][w][l] = h0; red1[1][w][l] = h1;
            red1[2][w][l] = h2; red1[3][w][l] = h3;
        }
        __syncthreads();   // S1

        // ===== phase 3: reduce + sigmoid; z in regs, r*h -> LDS =====
        float zreg[4];
        if (w < 4) {
            float4v s1v = ax0 + ax1 + red1[w][0][l] + red1[w][1][l]
                                  + red1[w][2][l] + red1[w][3][l];
            #pragma unroll
            for (int r = 0; r < 4; ++r) {
                const float sg = 1.f / (1.f + __expf(-(s1v[r] + bias1)));
                if (w < 2) zreg[r] = sg;
                else rhA[kg * 4 + r][(w - 2) * 16 + m_] =
                         sg * hL[kg * 4 + r][(w - 2) * 16 + m_];
            }
        }
        __syncthreads();   // S2

        // ===== phase 4: wave2 publishes rh; waves 0,1 P2 x-part =====
        if (w == 2) {
            short8v f;
            #pragma unroll
            for (int j = 0; j < 8; ++j)
                f[j] = (short)bf16_rne(rhA[m_][kg * 8 + j]);
            const uint4v u = __builtin_bit_cast(uint4v, f);
            short8v* dp = rhFrag + (size_t)s * 64 + l;
            asm volatile("global_store_dwordx4 %0, %1, off sc1" :: "v"(dp), "v"(u) : "memory");
            asm volatile("s_waitcnt vmcnt(0)" ::: "memory");
            if (l == 0)
                __hip_atomic_store(flagBase + s * 64 + 32, (unsigned)(t + 1),
                                   __ATOMIC_RELAXED, __HIP_MEMORY_SCOPE_AGENT);
        }
        float4v cx0 = {0.f,0.f,0.f,0.f}, cx1 = cx0;
        if (w < 2) {
            #pragma unroll
            for (int kt = 0; kt < 8; kt += 2) {
                cx0 = MFMA(xF[kt][l],     bx2[w][kt][l],     cx0, 0, 0, 0);
                cx1 = MFMA(xF[kt + 1][l], bx2[w][kt + 1][l], cx1, 0, 0, 0);
            }
        }

        // ===== phase 5: poll own 4 rh-producers, load, MFMA both hc tiles =====
        if (w < 4) {
            if (l < 4) {
                const unsigned* fp = flagBase + (4 * w + l) * 64 + 32;
                while (__hip_atomic_load(fp, __ATOMIC_RELAXED,
                                         __HIP_MEMORY_SCOPE_AGENT) < (unsigned)(t + 1))
                    __builtin_amdgcn_s_sleep(1);
            }
            uint4v u0, u1, u2, u3;
            const short8v* rp = rhFrag + (size_t)(4 * w) * 64 + l;
            asm volatile("global_load_dwordx4 %0, %1, off sc1" : "=v"(u0) : "v"(rp)       : "memory");
            asm volatile("global_load_dwordx4 %0, %1, off sc1" : "=v"(u1) : "v"(rp +  64) : "memory");
            asm volatile("global_load_dwordx4 %0, %1, off sc1" : "=v"(u2) : "v"(rp + 128) : "memory");
            asm volatile("global_load_dwordx4 %0, %1, off sc1" : "=v"(u3) : "v"(rp + 192) : "memory");
            asm volatile("s_waitcnt vmcnt(0)" ::: "memory");
            __builtin_amdgcn_sched_barrier(0);
            const short8v rf0 = __builtin_bit_cast(short8v, u0);
            const short8v rf1 = __builtin_bit_cast(short8v, u1);
            const short8v rf2 = __builtin_bit_cast(short8v, u2);
            const short8v rf3 = __builtin_bit_cast(short8v, u3);
            float4v c0 = {0.f,0.f,0.f,0.f}, c1 = c0;
            #pragma unroll
            for (int q = 0; q < 4; ++q) {
                const short8v a = (q == 0) ? rf0 : (q == 1) ? rf1 : (q == 2) ? rf2 : rf3;
                c0 = MFMA(a, wh2[0][q], c0, 0, 0, 0);
                c1 = MFMA(a, wh2[1][q], c1, 0, 0, 0);
            }
            red2[0][w][l] = c0; red2[1][w][l] = c1;
        }
        __syncthreads();   // S3

        // ===== phase 6: blend (waves 0,1); wave4 writes xF(t+1) =====
        if (w < 2) {
            float4v s2v = cx0 + cx1 + red2[w][0][l] + red2[w][1][l]
                                  + red2[w][2][l] + red2[w][3][l];
            #pragma unroll
            for (int r = 0; r < 4; ++r) {
                const int row = kg * 4 + r;
                const int cl = w * 16 + m_;
                const float hc = tanhf(s2v[r] + bias2);
                const float ho = hL[row][cl];
                hL[row][cl] = (1.f - zreg[r]) * ho + zreg[r] * (hc - ho) + zreg[r] * ho;
            }
        } else if (w == 4 && t + 1 < TT) {
            #pragma unroll
            for (int i = 0; i < 8; ++i) {
                const float4 v0 = xv[2 * i], v1 = xv[2 * i + 1];
                short8v f;
                f[0] = (short)bf16_rne(v0.x); f[1] = (short)bf16_rne(v0.y);
                f[2] = (short)bf16_rne(v0.z); f[3] = (short)bf16_rne(v0.w);
                f[4] = (short)bf16_rne(v1.x); f[5] = (short)bf16_rne(v1.y);
                f[6] = (short)bf16_rne(v1.z); f[7] = (short)bf16_rne(v1.w);
                xF[i][l] = f;
            }
        }
        __syncthreads();   // S4

        // ===== phase 7: wave4 publishes h(t); wave3 writes out from hL =====
        if (w == 4) {
            short8v f;
            #pragma unroll
            for (int j = 0; j < 8; ++j)
                f[j] = (short)bf16_rne(hL[m_][kg * 8 + j]);
            const uint4v u = __builtin_bit_cast(uint4v, f);
            short8v* dp = hFrag + (size_t)s * 64 + l;
            asm volatile("global_store_dwordx4 %0, %1, off sc1" :: "v"(dp), "v"(u) : "memory");
            asm volatile("s_waitcnt vmcnt(0)" ::: "memory");
            if (l == 0)
                __hip_atomic_store(flagBase + s * 64, (unsigned)(t + 1),
                                   __ATOMIC_RELAXED, __HIP_MEMORY_SCOPE_AGENT);
        } else if (w == 3) {
            float* op = out + (size_t)(g * 16 + m_) * (TT * HH) + (size_t)t * HH
                            + s * 32 + kg * 8;
            float4 o0, o1;
            o0.x = hL[m_][kg * 8 + 0]; o0.y = hL[m_][kg * 8 + 1];
            o0.z = hL[m_][kg * 8 + 2]; o0.w = hL[m_][kg * 8 + 3];
            o1.x = hL[m_][kg * 8 + 4]; o1.y = hL[m_][kg * 8 + 5];
            o1.z = hL[m_][kg * 8 + 6]; o1.w = hL[m_][kg * 8 + 7];
            *(float4*)op = o0;
            *(float4*)(op + 4) = o1;
        }
    }
}

// ---------------- fallback (round-3 kernel) if ws too small ----------------
#define NWG_FB 64
#define NTHR_FB 512
__global__ __launch_bounds__(NTHR_FB, 1) void gru_rowsplit(
    const float* __restrict__ x,
    const float* __restrict__ Wz, const float* __restrict__ bz,
    const float* __restrict__ Wr, const float* __restrict__ br,
    const float* __restrict__ Wh, const float* __restrict__ bh,
    float* __restrict__ out)
{
    __shared__ float comb_i [KK][2];
    __shared__ float comb2_i[KK][2];
    __shared__ float z_s[2][HH];
    __shared__ float red1[8][257];
    __shared__ float red2[24][129];

    const int tid  = threadIdx.x;
    const int row0 = blockIdx.x * 2;
    const int kh = tid >> 8;
    const int t1 = tid & 255;
    const int n1 = t1 * 4;
    const float* __restrict__ w1 =
        ((n1 < HH) ? (Wz + n1) : (Wr + (n1 - HH))) + (size_t)(kh * 384) * HH;
    const int kq = tid >> 7;
    const int t2 = tid & 127;
    const int n2 = t2 * 4;
    const float* __restrict__ w2 = Wh + n2 + (size_t)(kq * 192) * HH;

    float b1[4], b2[4];
    #pragma unroll
    for (int j = 0; j < 4; ++j) {
        b1[j] = (n1 + j < HH) ? bz[n1 + j] : br[n1 + j - HH];
        b2[j] = bh[n2 + j];
    }
    for (int idx = tid; idx < HH * 2; idx += NTHR_FB)
        comb_i[II + (idx >> 1)][idx & 1] = 0.f;
    __syncthreads();

    for (int t = 0; t < TT; ++t) {
        {
            const int r = tid >> 8, k = tid & 255;
            const float v = x[(size_t)(row0 + r) * (TT * II) + (size_t)t * II + k];
            comb_i [k][r] = v;
            comb2_i[k][r] = v;
        }
        __syncthreads();
        float a00=0,a01=0,a02=0,a03=0,a10=0,a11=0,a12=0,a13=0;
        {
            const int kb = kh * 384;
            #pragma unroll 8
            for (int k = 0; k < 384; ++k) {
                const float4 w = *(const float4*)(w1 + (size_t)k * HH);
                const float2 a = *(const float2*)&comb_i[kb + k][0];
                a00 += a.x*w.x; a01 += a.x*w.y; a02 += a.x*w.z; a03 += a.x*w.w;
                a10 += a.y*w.x; a11 += a.y*w.y; a12 += a.y*w.z; a13 += a.y*w.w;
            }
        }
        if (kh == 1) {
            red1[0][t1]=a00; red1[1][t1]=a01; red1[2][t1]=a02; red1[3][t1]=a03;
            red1[4][t1]=a10; red1[5][t1]=a11; red1[6][t1]=a12; red1[7][t1]=a13;
        }
        __syncthreads();
        if (kh == 0) {
            float accv[2][4] = {{a00,a01,a02,a03},{a10,a11,a12,a13}};
            #pragma unroll
            for (int r = 0; r < 2; ++r) {
                #pragma unroll
                for (int j = 0; j < 4; ++j) {
                    const int n = n1 + j;
                    const float v = accv[r][j] + red1[r*4+j][t1] + b1[j];
                    const float sg = 1.f / (1.f + __expf(-v));
                    if (n < HH) z_s[r][n] = sg;
                    else {
                        const int nh = n - HH;
                        comb2_i[II + nh][r] = sg * comb_i[II + nh][r];
                    }
                }
            }
        }
        __syncthreads();
        float c00=0,c01=0,c02=0,c03=0,c10=0,c11=0,c12=0,c13=0;
        {
            const int kb = kq * 192;
            #pragma unroll 8
            for (int k = 0; k < 192; ++k) {
                const float4 w = *(const float4*)(w2 + (size_t)k * HH);
                const float2 a = *(const float2*)&comb2_i[kb + k][0];
                c00 += a.x*w.x; c01 += a.x*w.y; c02 += a.x*w.z; c03 += a.x*w.w;
                c10 += a.y*w.x; c11 += a.y*w.y; c12 += a.y*w.z; c13 += a.y*w.w;
            }
        }
        if (kq > 0) {
            const int base = (kq - 1) * 8;
            red2[base+0][t2]=c00; red2[base+1][t2]=c01;
            red2[base+2][t2]=c02; red2[base+3][t2]=c03;
            red2[base+4][t2]=c10; red2[base+5][t2]=c11;
            red2[base+6][t2]=c12; red2[base+7][t2]=c13;
        }
        __syncthreads();
        if (kq == 0) {
            float accv[2][4] = {{c00,c01,c02,c03},{c10,c11,c12,c13}};
            #pragma unroll
            for (int r = 0; r < 2; ++r) {
                float hn4[4];
                #pragma unroll
                for (int j = 0; j < 4; ++j) {
                    const int n = n2 + j;
                    const int jj = r * 4 + j;
                    const float v = accv[r][j] + red2[jj][t2] + red2[8+jj][t2]
                                  + red2[16+jj][t2] + b2[j];
                    const float hc = tanhf(v);
                    const float zv = z_s[r][n];
                    const float ho = comb_i[II + n][r];
                    const float hn = (1.f - zv) * ho + zv * hc;
                    comb_i[II + n][r] = hn;
                    hn4[j] = hn;
                }
                *(float4*)&out[(size_t)(row0 + r) * (TT * HH) + (size_t)t * HH + n2] =
                    make_float4(hn4[0], hn4[1], hn4[2], hn4[3]);
            }
        }
        __syncthreads();
    }
}

extern "C" void kernel_launch(void* const* d_in, const int* in_sizes, int n_in,
                              void* d_out, int out_size, void* d_ws, size_t ws_size,
                              hipStream_t stream) {
    const float* x  = (const float*)d_in[0];
    const float* Wz = (const float*)d_in[1];
    const float* bz = (const float*)d_in[2];
    const float* Wr = (const float*)d_in[3];
    const float* br = (const float*)d_in[4];
    const float* Wh = (const float*)d_in[5];
    const float* bh = (const float*)d_in[6];
    float* out = (float*)d_out;

    if (ws_size < WS_NEED) {
        gru_rowsplit<<<NWG_FB, NTHR_FB, 0, stream>>>(x, Wz, bz, Wr, br, Wh, bh, out);
        return;
    }

    char* ws = (char*)d_ws;
    unsigned* bars = (unsigned*)(ws + BARS_OFF);
    short8v*  wB   = (short8v*)(ws + WFRAG_OFF);
    char*     gs   = ws + GS_OFF;

    hipMemsetAsync(bars, 0, BARS_SZ, stream);
    hipMemsetAsync(gs, 0, 8 * (size_t)GS_STRIDE, stream);   // h0 = 0 frags
    repack_w<<<96, 256, 0, stream>>>(Wz, Wr, Wh, wB);
    gru_mfma<<<128, NT_MAIN, 0, stream>>>(x, bz, br, bh, out, wB, gs, bars);
}